// Round 1
// baseline (177.074 us; speedup 1.0000x reference)
//
#include <hip/hip_runtime.h>

#define S_LEN 4096
#define B_SZ 8
#define KTOT 384            // M (256) + D (128)
#define CPROWS 532          // ceil((4096+127)/8)+pad rows per parity copy
#define HN_OFF 8388608      // 8*4096*256

typedef __attribute__((ext_vector_type(8))) short short8;
typedef __attribute__((ext_vector_type(4))) float f32x4;

__device__ __forceinline__ short f2bf(float f) {
  union { float f; unsigned u; } v; v.f = f;
  unsigned r = v.u + 0x7FFFu + ((v.u >> 16) & 1u);
  return (short)(r >> 16);
}

// K1a: u = relu(x @ W_u + b_u); also write x as bf16 into mx[..., 256:384]
__global__ __launch_bounds__(256) void k_u(const float* __restrict__ x,
                                           const float* __restrict__ Wu,
                                           const float* __restrict__ bu,
                                           float* __restrict__ u,
                                           short* __restrict__ mx) {
  int row = blockIdx.x * 4 + (threadIdx.x >> 6);   // b*4096 + t
  int l = threadIdx.x & 63;
  const float* xr = x + (size_t)row * 128;
  float x0 = xr[l], x1 = xr[l + 64];
  float s = x0 * Wu[l] + x1 * Wu[l + 64];
  #pragma unroll
  for (int m = 32; m >= 1; m >>= 1) s += __shfl_xor(s, m, 64);
  short* mrow = mx + (size_t)row * KTOT + 256;
  mrow[l]      = f2bf(x0);
  mrow[l + 64] = f2bf(x1);
  if (l == 0) {
    float v = s + bu[0];
    u[row] = v > 0.0f ? v : 0.0f;
  }
}

// K1b: build 8 parity-shifted copies of reversed zero-extended u (bf16).
// copy layout: cp[((b*8+p)*CPROWS + row)*8 + j] = u_rev[8*row + p + j]
// u_rev[e] = u[b][4095-e] for e<4096 else 0.
__global__ __launch_bounds__(256) void k_cp(const float* __restrict__ u,
                                            short* __restrict__ cp) {
  int idx = blockIdx.x * 256 + threadIdx.x;
  if (idx >= B_SZ * 8 * CPROWS * 8) return;
  int j   = idx & 7;
  int row = (idx >> 3) % CPROWS;
  int rem = (idx >> 3) / CPROWS;
  int p = rem & 7;
  int b = rem >> 3;
  int e = 8 * row + p + j;
  short v = 0;
  if (e < S_LEN) v = f2bf(u[b * S_LEN + (S_LEN - 1 - e)]);
  cp[idx] = v;
}

__global__ __launch_bounds__(256) void k_cvt(const float* __restrict__ in,
                                             short* __restrict__ out, int n) {
  int i = blockIdx.x * 256 + threadIdx.x;
  if (i < n) out[i] = f2bf(in[i]);
}

// W_h^T as bf16: wht[n*384 + k] = W_h[k*256 + n]
__global__ __launch_bounds__(256) void k_wht(const float* __restrict__ Wh,
                                             short* __restrict__ wht) {
  int i = blockIdx.x * 256 + threadIdx.x;
  if (i >= 256 * KTOT) return;
  int n = i / KTOT, k = i % KTOT;
  wht[i] = f2bf(Wh[k * 256 + n]);
}

// K2: m[b][s][q] = sum_{tau<=s} u[b][s-tau] * H[q][tau], written bf16 into mx[...,0:256]
// A (Toeplitz u) fragments from parity copies; B fragments directly from H_bf16 rows.
__global__ __launch_bounds__(256) void k_conv(const short* __restrict__ cp,
                                              const short* __restrict__ Hb,
                                              short* __restrict__ mx) {
  int idx = blockIdx.x;                 // 512 blocks: st descending first for balance
  int st  = 31 - (idx >> 4);
  int rem = idx & 15;
  int qt  = rem & 1;
  int b   = rem >> 1;
  int s0 = st << 7, q0 = qt << 7;

  int tid = threadIdx.x;
  int l = tid & 63, wid = tid >> 6;
  int wr = wid >> 1, wc = wid & 1;      // wave tile 64(s) x 64(q)
  int lm = l & 15, kg = l >> 4;

  int sbase = s0 + wr * 64 + lm;
  int e00 = (S_LEN - 1) - sbase + 8 * kg;       // u_rev index at tau=0, mf=0, j=0
  int p = e00 & 7;
  const short* Abase = cp + ((size_t)((b * 8 + p) * CPROWS + (e00 >> 3))) * 8;
  const short* Bbase = Hb + (size_t)(q0 + wc * 64 + lm) * S_LEN + 8 * kg;

  f32x4 acc[4][4];
  #pragma unroll
  for (int i = 0; i < 4; ++i)
    #pragma unroll
    for (int jn = 0; jn < 4; ++jn)
      acc[i][jn] = (f32x4){0.0f, 0.0f, 0.0f, 0.0f};

  int nsteps = 4 * st + 4;

  short8 ac[4], bc[4];
  #pragma unroll
  for (int mf = 0; mf < 4; ++mf) ac[mf] = *(const short8*)(Abase - 16 * mf);
  #pragma unroll
  for (int nf = 0; nf < 4; ++nf) bc[nf] = *(const short8*)(Bbase + nf * 16 * S_LEN);

  for (int t = 0; ; ++t) {
    bool more = (t + 1 < nsteps);
    short8 an[4], bn[4];
    if (more) {
      const short* a2 = Abase + (t + 1) * 32;
      const short* b2 = Bbase + (t + 1) * 32;
      #pragma unroll
      for (int mf = 0; mf < 4; ++mf) an[mf] = *(const short8*)(a2 - 16 * mf);
      #pragma unroll
      for (int nf = 0; nf < 4; ++nf) bn[nf] = *(const short8*)(b2 + nf * 16 * S_LEN);
    }
    #pragma unroll
    for (int mf = 0; mf < 4; ++mf)
      #pragma unroll
      for (int nf = 0; nf < 4; ++nf)
        acc[mf][nf] = __builtin_amdgcn_mfma_f32_16x16x32_bf16(ac[mf], bc[nf], acc[mf][nf], 0, 0, 0);
    if (!more) break;
    #pragma unroll
    for (int mf = 0; mf < 4; ++mf) ac[mf] = an[mf];
    #pragma unroll
    for (int nf = 0; nf < 4; ++nf) bc[nf] = bn[nf];
  }

  // C/D layout: col = lane&15, row = (lane>>4)*4 + reg
  #pragma unroll
  for (int mf = 0; mf < 4; ++mf)
    #pragma unroll
    for (int nf = 0; nf < 4; ++nf)
      #pragma unroll
      for (int j = 0; j < 4; ++j) {
        int s = s0 + wr * 64 + mf * 16 + kg * 4 + j;
        int q = q0 + wc * 64 + nf * 16 + lm;
        mx[(size_t)(b * S_LEN + s) * KTOT + q] = f2bf(acc[mf][nf][j]);
      }
}

// K3: h = relu(mx @ W_h + b_h); h_n extra write for s==4095 rows.
__global__ __launch_bounds__(256) void k_gemm2(const short* __restrict__ mx,
                                               const short* __restrict__ wht,
                                               const float* __restrict__ bh,
                                               float* __restrict__ out) {
  int idx = blockIdx.x;       // 512 = 256 row-tiles * 2 n-tiles
  int nt = idx & 1;
  int rt = idx >> 1;
  int R0 = rt << 7;

  int tid = threadIdx.x;
  int l = tid & 63, wid = tid >> 6;
  int wr = wid >> 1, wc = wid & 1;
  int lm = l & 15, kg = l >> 4;

  const short* Abase = mx  + (size_t)(R0 + wr * 64 + lm) * KTOT + 8 * kg;
  const short* Bbase = wht + (size_t)(nt * 128 + wc * 64 + lm) * KTOT + 8 * kg;

  f32x4 acc[4][4];
  #pragma unroll
  for (int i = 0; i < 4; ++i)
    #pragma unroll
    for (int jn = 0; jn < 4; ++jn)
      acc[i][jn] = (f32x4){0.0f, 0.0f, 0.0f, 0.0f};

  short8 ac[4], bc[4];
  #pragma unroll
  for (int mf = 0; mf < 4; ++mf) ac[mf] = *(const short8*)(Abase + mf * 16 * KTOT);
  #pragma unroll
  for (int nf = 0; nf < 4; ++nf) bc[nf] = *(const short8*)(Bbase + nf * 16 * KTOT);

  for (int t = 0; ; ++t) {
    bool more = (t + 1 < 12);
    short8 an[4], bn[4];
    if (more) {
      const short* a2 = Abase + (t + 1) * 32;
      const short* b2 = Bbase + (t + 1) * 32;
      #pragma unroll
      for (int mf = 0; mf < 4; ++mf) an[mf] = *(const short8*)(a2 + mf * 16 * KTOT);
      #pragma unroll
      for (int nf = 0; nf < 4; ++nf) bn[nf] = *(const short8*)(b2 + nf * 16 * KTOT);
    }
    #pragma unroll
    for (int mf = 0; mf < 4; ++mf)
      #pragma unroll
      for (int nf = 0; nf < 4; ++nf)
        acc[mf][nf] = __builtin_amdgcn_mfma_f32_16x16x32_bf16(ac[mf], bc[nf], acc[mf][nf], 0, 0, 0);
    if (!more) break;
    #pragma unroll
    for (int mf = 0; mf < 4; ++mf) ac[mf] = an[mf];
    #pragma unroll
    for (int nf = 0; nf < 4; ++nf) bc[nf] = bn[nf];
  }

  #pragma unroll
  for (int mf = 0; mf < 4; ++mf)
    #pragma unroll
    for (int nf = 0; nf < 4; ++nf) {
      int n = nt * 128 + wc * 64 + nf * 16 + lm;
      float bias = bh[n];
      #pragma unroll
      for (int j = 0; j < 4; ++j) {
        int R = R0 + wr * 64 + mf * 16 + kg * 4 + j;
        float v = acc[mf][nf][j] + bias;
        v = v > 0.0f ? v : 0.0f;
        out[(size_t)R * 256 + n] = v;
        if ((R & (S_LEN - 1)) == (S_LEN - 1))
          out[HN_OFF + (R >> 12) * 256 + n] = v;
      }
    }
}

extern "C" void kernel_launch(void* const* d_in, const int* in_sizes, int n_in,
                              void* d_out, int out_size, void* d_ws, size_t ws_size,
                              hipStream_t stream) {
  const float* x  = (const float*)d_in[0];
  const float* Wu = (const float*)d_in[1];
  const float* bu = (const float*)d_in[2];
  const float* Wh = (const float*)d_in[3];
  const float* bh = (const float*)d_in[4];
  const float* H  = (const float*)d_in[5];
  float* out = (float*)d_out;

  char* ws = (char*)d_ws;
  float* u   = (float*)ws;                                   // 131072 B
  short* cp  = (short*)(ws + 131072);                        // 544768 B
  short* Hb  = (short*)(ws + 131072 + 544768);               // 2097152 B
  short* wht = (short*)(ws + 131072 + 544768 + 2097152);     // 196608 B
  short* mx  = (short*)(ws + 131072 + 544768 + 2097152 + 196608); // 25165824 B

  k_u  <<<8192, 256, 0, stream>>>(x, Wu, bu, u, mx);
  k_cvt<<<4096, 256, 0, stream>>>(H, Hb, 256 * S_LEN);
  k_wht<<<384,  256, 0, stream>>>(Wh, wht);
  k_cp <<<1064, 256, 0, stream>>>(u, cp);
  k_conv<<<512, 256, 0, stream>>>(cp, Hb, mx);
  k_gemm2<<<512, 256, 0, stream>>>(mx, wht, bh, out);
}

// Round 2
// 105.768 us; speedup vs baseline: 1.6742x; 1.6742x over previous
//
#include <hip/hip_runtime.h>

#define S_LEN 4096
#define B_SZ 8
#define KTOT 384            // M (256) + D (128)
#define CPROWS 544          // 8-elem rows per parity copy (zero-padded past 4096)
#define HN_OFF 8388608      // 8*4096*256

typedef __attribute__((ext_vector_type(8))) short short8;
typedef __attribute__((ext_vector_type(4))) float f32x4;

typedef const __attribute__((address_space(1))) unsigned int as1_u32;
typedef __attribute__((address_space(3))) unsigned int as3_u32;

__device__ __forceinline__ void gload16(const short* g, short* l) {
  __builtin_amdgcn_global_load_lds((as1_u32*)g, (as3_u32*)l, 16, 0, 0);
}

__device__ __forceinline__ short f2bf(float f) {
  union { float f; unsigned u; } v; v.f = f;
  unsigned r = v.u + 0x7FFFu + ((v.u >> 16) & 1u);
  return (short)(r >> 16);
}

// K1a: u = relu(x @ W_u + b_u); also write x as bf16 into mx[..., 256:384]
__global__ __launch_bounds__(256) void k_u(const float* __restrict__ x,
                                           const float* __restrict__ Wu,
                                           const float* __restrict__ bu,
                                           float* __restrict__ u,
                                           short* __restrict__ mx) {
  int row = blockIdx.x * 4 + (threadIdx.x >> 6);   // b*4096 + t
  int l = threadIdx.x & 63;
  const float* xr = x + (size_t)row * 128;
  float x0 = xr[l], x1 = xr[l + 64];
  float s = x0 * Wu[l] + x1 * Wu[l + 64];
  #pragma unroll
  for (int m = 32; m >= 1; m >>= 1) s += __shfl_xor(s, m, 64);
  short* mrow = mx + (size_t)row * KTOT + 256;
  mrow[l]      = f2bf(x0);
  mrow[l + 64] = f2bf(x1);
  if (l == 0) {
    float v = s + bu[0];
    u[row] = v > 0.0f ? v : 0.0f;
  }
}

// K1b: 8 parity-shifted copies of reversed zero-extended u (bf16).
// cp[((b*8+p)*CPROWS + row)*8 + j] = u_rev[8*row + p + j]; u_rev[e]=u[b][4095-e], 0 for e>=4096.
__global__ __launch_bounds__(256) void k_cp(const float* __restrict__ u,
                                            short* __restrict__ cp) {
  int idx = blockIdx.x * 256 + threadIdx.x;
  if (idx >= B_SZ * 8 * CPROWS * 8) return;
  int j   = idx & 7;
  int row = (idx >> 3) % CPROWS;
  int rem = (idx >> 3) / CPROWS;
  int p = rem & 7;
  int b = rem >> 3;
  int e = 8 * row + p + j;
  short v = 0;
  if (e < S_LEN) v = f2bf(u[b * S_LEN + (S_LEN - 1 - e)]);
  cp[idx] = v;
}

__global__ __launch_bounds__(256) void k_cvt(const float* __restrict__ in,
                                             short* __restrict__ out, int n) {
  int i = blockIdx.x * 256 + threadIdx.x;
  if (i < n) out[i] = f2bf(in[i]);
}

// W_h^T as bf16: wht[n*384 + k] = W_h[k*256 + n]
__global__ __launch_bounds__(256) void k_wht(const float* __restrict__ Wh,
                                             short* __restrict__ wht) {
  int i = blockIdx.x * 256 + threadIdx.x;
  if (i >= 256 * KTOT) return;
  int n = i / KTOT, k = i % KTOT;
  wht[i] = f2bf(Wh[k * 256 + n]);
}

// K2: LDS-staged Toeplitz GEMM. m[b][s][q] = sum_tau u[b][s-tau]*H[q][tau] -> bf16 mx[...,0:256]
// Tile 128(s)x128(q), BK=64 (2 MFMA substeps), double-buffered LDS, global_load_lds w=16.
__global__ __launch_bounds__(256) void k_conv(const short* __restrict__ cp,
                                              const short* __restrict__ Hb,
                                              short* __restrict__ mx) {
  // B tile: [128 rows(q)][64 tau] bf16, XOR-swizzled within row (16B chunks).
  // A window: rows of 8 parities: byte (e-F0)*16 holds u_rev[e..e+7]. 32 rows x 128B.
  __shared__ __attribute__((aligned(16))) short Bt[2][128 * 64];
  __shared__ __attribute__((aligned(16))) short Aw[2][32 * 64];

  int idx = blockIdx.x;                 // st descending for balance
  int st  = 31 - (idx >> 4);
  int rem = idx & 15;
  int qt  = rem & 1;
  int b   = rem >> 1;
  int s0 = st << 7, q0 = qt << 7;

  int tid = threadIdx.x;
  int lane = tid & 63, wid = tid >> 6;
  int wr = wid >> 1, wc = wid & 1;      // wave tile 64(s) x 64(q)
  int lm = lane & 15, kg = lane >> 4;
  int l3 = lane >> 3, l7 = lane & 7;
  int lm7 = lm & 7;

  // ---- staging source bases (advance by 64 shorts per chunk) ----
  // B: wave wid, instr i: row r = wid*32+i*8+l3; src col shorts = c*64 + ((l7^l3)<<3)
  const short* bSrc = Hb + (size_t)(q0 + wid * 32 + l3) * S_LEN + ((l7 ^ l3) << 3);
  // A: src short idx = ((b*8+l7)*CPROWS + (496-16*st) + wid*8 + l3)*8 + c*64
  const short* aSrc = cp + ((size_t)(b * 8 + l7) * CPROWS + (496 - 16 * st) + wid * 8 + l3) * 8;

  // ---- fragment read bases ----
  int aOff = (127 - wr * 64 - lm + 8 * kg) * 8;        // shorts; frag: + 256*ks - 128*mf
  int bRow = (wc * 64 + lm) * 64;                      // shorts; frag: + nf*1024 + xs(ks)

  f32x4 acc[4][4];
  #pragma unroll
  for (int i = 0; i < 4; ++i)
    #pragma unroll
    for (int jn = 0; jn < 4; ++jn)
      acc[i][jn] = (f32x4){0.0f, 0.0f, 0.0f, 0.0f};

  int nchunks = 2 * st + 2;

  // prologue: stage chunk 0 into buffer 0
  #pragma unroll
  for (int i = 0; i < 4; ++i)
    gload16(bSrc + (size_t)i * 8 * S_LEN, Bt[0] + (wid * 32 + i * 8) * 64);
  gload16(aSrc, Aw[0] + (wid * 8) * 64);
  __syncthreads();

  for (int c = 0; c < nchunks; ++c) {
    int cur = c & 1;
    const short* AwB = Aw[cur];
    const short* BtB = Bt[cur];
    if (c + 1 < nchunks) {
      int nb = cur ^ 1;
      int coff = (c + 1) * 64;
      #pragma unroll
      for (int i = 0; i < 4; ++i)
        gload16(bSrc + (size_t)i * 8 * S_LEN + coff, Bt[nb] + (wid * 32 + i * 8) * 64);
      gload16(aSrc + coff, Aw[nb] + (wid * 8) * 64);
    }
    #pragma unroll
    for (int ks = 0; ks < 2; ++ks) {
      short8 af[4], bf[4];
      #pragma unroll
      for (int mf = 0; mf < 4; ++mf)
        af[mf] = *(const short8*)(AwB + aOff + 256 * ks - 128 * mf);
      int xs = ((ks << 5)) | 0;
      #pragma unroll
      for (int nf = 0; nf < 4; ++nf) {
        int col = ((ks << 5) + (kg << 3)) ^ (lm7 << 3);
        bf[nf] = *(const short8*)(BtB + bRow + nf * 1024 + col);
      }
      (void)xs;
      #pragma unroll
      for (int mf = 0; mf < 4; ++mf)
        #pragma unroll
        for (int nf = 0; nf < 4; ++nf)
          acc[mf][nf] = __builtin_amdgcn_mfma_f32_16x16x32_bf16(af[mf], bf[nf], acc[mf][nf], 0, 0, 0);
    }
    __syncthreads();
  }

  // C/D layout: col = lane&15, row = (lane>>4)*4 + reg
  #pragma unroll
  for (int mf = 0; mf < 4; ++mf)
    #pragma unroll
    for (int nf = 0; nf < 4; ++nf)
      #pragma unroll
      for (int j = 0; j < 4; ++j) {
        int s = s0 + wr * 64 + mf * 16 + kg * 4 + j;
        int q = q0 + wc * 64 + nf * 16 + lm;
        mx[(size_t)(b * S_LEN + s) * KTOT + q] = f2bf(acc[mf][nf][j]);
      }
}

// K3: h = relu(mx @ W_h + b_h); h_n extra write for s==4095 rows.
__global__ __launch_bounds__(256) void k_gemm2(const short* __restrict__ mx,
                                               const short* __restrict__ wht,
                                               const float* __restrict__ bh,
                                               float* __restrict__ out) {
  int idx = blockIdx.x;       // 512 = 256 row-tiles * 2 n-tiles
  int nt = idx & 1;
  int rt = idx >> 1;
  int R0 = rt << 7;

  int tid = threadIdx.x;
  int l = tid & 63, wid = tid >> 6;
  int wr = wid >> 1, wc = wid & 1;
  int lm = l & 15, kg = l >> 4;

  const short* Abase = mx  + (size_t)(R0 + wr * 64 + lm) * KTOT + 8 * kg;
  const short* Bbase = wht + (size_t)(nt * 128 + wc * 64 + lm) * KTOT + 8 * kg;

  f32x4 acc[4][4];
  #pragma unroll
  for (int i = 0; i < 4; ++i)
    #pragma unroll
    for (int jn = 0; jn < 4; ++jn)
      acc[i][jn] = (f32x4){0.0f, 0.0f, 0.0f, 0.0f};

  short8 ac[4], bc[4];
  #pragma unroll
  for (int mf = 0; mf < 4; ++mf) ac[mf] = *(const short8*)(Abase + mf * 16 * KTOT);
  #pragma unroll
  for (int nf = 0; nf < 4; ++nf) bc[nf] = *(const short8*)(Bbase + nf * 16 * KTOT);

  for (int t = 0; ; ++t) {
    bool more = (t + 1 < 12);
    short8 an[4], bn[4];
    if (more) {
      const short* a2 = Abase + (t + 1) * 32;
      const short* b2 = Bbase + (t + 1) * 32;
      #pragma unroll
      for (int mf = 0; mf < 4; ++mf) an[mf] = *(const short8*)(a2 + mf * 16 * KTOT);
      #pragma unroll
      for (int nf = 0; nf < 4; ++nf) bn[nf] = *(const short8*)(b2 + nf * 16 * KTOT);
    }
    #pragma unroll
    for (int mf = 0; mf < 4; ++mf)
      #pragma unroll
      for (int nf = 0; nf < 4; ++nf)
        acc[mf][nf] = __builtin_amdgcn_mfma_f32_16x16x32_bf16(ac[mf], bc[nf], acc[mf][nf], 0, 0, 0);
    if (!more) break;
    #pragma unroll
    for (int mf = 0; mf < 4; ++mf) ac[mf] = an[mf];
    #pragma unroll
    for (int nf = 0; nf < 4; ++nf) bc[nf] = bn[nf];
  }

  #pragma unroll
  for (int mf = 0; mf < 4; ++mf)
    #pragma unroll
    for (int nf = 0; nf < 4; ++nf) {
      int n = nt * 128 + wc * 64 + nf * 16 + lm;
      float bias = bh[n];
      #pragma unroll
      for (int j = 0; j < 4; ++j) {
        int R = R0 + wr * 64 + mf * 16 + kg * 4 + j;
        float v = acc[mf][nf][j] + bias;
        v = v > 0.0f ? v : 0.0f;
        out[(size_t)R * 256 + n] = v;
        if ((R & (S_LEN - 1)) == (S_LEN - 1))
          out[HN_OFF + (R >> 12) * 256 + n] = v;
      }
    }
}

extern "C" void kernel_launch(void* const* d_in, const int* in_sizes, int n_in,
                              void* d_out, int out_size, void* d_ws, size_t ws_size,
                              hipStream_t stream) {
  const float* x  = (const float*)d_in[0];
  const float* Wu = (const float*)d_in[1];
  const float* bu = (const float*)d_in[2];
  const float* Wh = (const float*)d_in[3];
  const float* bh = (const float*)d_in[4];
  const float* H  = (const float*)d_in[5];
  float* out = (float*)d_out;

  char* ws = (char*)d_ws;
  float* u   = (float*)ws;                         // 131072 B
  short* cp  = (short*)(ws + 131072);              // 8*8*544*8*2 = 557056 B
  short* Hb  = (short*)(ws + 688128);              // 2097152 B
  short* wht = (short*)(ws + 2785280);             // 196608 B
  short* mx  = (short*)(ws + 2981888);             // 25165824 B

  k_u  <<<8192, 256, 0, stream>>>(x, Wu, bu, u, mx);
  k_cvt<<<4096, 256, 0, stream>>>(H, Hb, 256 * S_LEN);
  k_wht<<<384,  256, 0, stream>>>(Wh, wht);
  k_cp <<<1088, 256, 0, stream>>>(u, cp);
  k_conv<<<512, 256, 0, stream>>>(cp, Hb, mx);
  k_gemm2<<<512, 256, 0, stream>>>(mx, wht, bh, out);
}

// Round 3
// 92.901 us; speedup vs baseline: 1.9060x; 1.1385x over previous
//
#include <hip/hip_runtime.h>

#define S_LEN 4096
#define B_SZ 8
#define KTOT 384            // M (256) + D (128)
#define CPROWS 544          // 8-elem rows per parity copy (zero-padded past 4096)
#define HN_OFF 8388608      // 8*4096*256

typedef __attribute__((ext_vector_type(8))) short short8;
typedef __attribute__((ext_vector_type(4))) float f32x4;

typedef const __attribute__((address_space(1))) unsigned int as1_u32;
typedef __attribute__((address_space(3))) unsigned int as3_u32;

__device__ __forceinline__ void gload16(const short* g, short* l) {
  __builtin_amdgcn_global_load_lds((as1_u32*)g, (as3_u32*)l, 16, 0, 0);
}

__device__ __forceinline__ short f2bf(float f) {
  union { float f; unsigned u; } v; v.f = f;
  unsigned r = v.u + 0x7FFFu + ((v.u >> 16) & 1u);
  return (short)(r >> 16);
}

// K1: u = relu(x@W_u+b_u); x->bf16 into mx[...,256:384]; u scattered into the
// 8 parity-shifted reversed copies cp (folds old k_cp). Blocks >= 8192 zero the
// e>=4096 tail of cp (d_ws is poisoned, not zeroed).
__global__ __launch_bounds__(256) void k_u(const float* __restrict__ x,
                                           const float* __restrict__ Wu,
                                           const float* __restrict__ bu,
                                           short* __restrict__ mx,
                                           short* __restrict__ cp) {
  if (blockIdx.x >= 8192) {
    int idx = (blockIdx.x - 8192) * 256 + threadIdx.x;   // b(8)*p(8)*r(36)*j(8)
    if (idx < 18432) {
      int j = idx & 7;
      int r = 508 + ((idx >> 3) % 36);
      int rem = (idx >> 3) / 36;
      int p = rem & 7;
      int b = rem >> 3;
      int e = 8 * r + p + j;
      if (b < 8 && r < CPROWS && e >= S_LEN)
        cp[((size_t)(b * 8 + p) * CPROWS + r) * 8 + j] = 0;
    }
    return;
  }
  int row = blockIdx.x * 4 + (threadIdx.x >> 6);   // b*4096 + t
  int l = threadIdx.x & 63;
  const float* xr = x + (size_t)row * 128;
  float x0 = xr[l], x1 = xr[l + 64];
  float s = x0 * Wu[l] + x1 * Wu[l + 64];
  #pragma unroll
  for (int m = 32; m >= 1; m >>= 1) s += __shfl_xor(s, m, 64);
  short* mrow = mx + (size_t)row * KTOT + 256;
  mrow[l]      = f2bf(x0);
  mrow[l + 64] = f2bf(x1);
  float v = s + bu[0];
  v = v > 0.0f ? v : 0.0f;
  short vb = f2bf(v);
  if (l < 8) {
    int t = row & (S_LEN - 1);
    int b = row >> 12;
    int e = (S_LEN - 1) - t;       // u_rev index of this element
    int p = l;
    if (e >= p) {
      int d = e - p;
      cp[((size_t)(b * 8 + p) * CPROWS + (d >> 3)) * 8 + (d & 7)] = vb;
    }
  }
}

// K_misc: H->bf16 (blocks <4096) and W_h^T->bf16 (blocks >=4096)
__global__ __launch_bounds__(256) void k_misc(const float* __restrict__ H,
                                              const float* __restrict__ Wh,
                                              short* __restrict__ Hb,
                                              short* __restrict__ wht) {
  int i = blockIdx.x * 256 + threadIdx.x;
  if (blockIdx.x < 4096) {
    Hb[i] = f2bf(H[i]);
  } else {
    int j = i - 4096 * 256;
    if (j < 256 * KTOT) {
      int n = j / KTOT, k = j % KTOT;
      wht[j] = f2bf(Wh[k * 256 + n]);
    }
  }
}

// K2: pipelined Toeplitz GEMM. m[b][s][q] = sum_tau u[b][s-tau]*H[q][tau].
// 128x128 tile, BK=64, 4-slot LDS ring, counted vmcnt, 1 barrier/chunk.
__global__ __launch_bounds__(256) void k_conv(const short* __restrict__ cp,
                                              const short* __restrict__ Hb,
                                              short* __restrict__ mx) {
  __shared__ __attribute__((aligned(16))) short Bt[4][128 * 64];  // 64 KB
  __shared__ __attribute__((aligned(16))) short Aw[4][32 * 64];   // 16 KB

  int idx = blockIdx.x;                 // st descending: LPT scheduling
  int st  = 31 - (idx >> 4);
  int rem = idx & 15;
  int qt  = rem & 1;
  int b   = rem >> 1;
  int s0 = st << 7, q0 = qt << 7;

  int tid = threadIdx.x;
  int lane = tid & 63, wid = tid >> 6;
  int wr = wid >> 1, wc = wid & 1;      // wave tile 64(s) x 64(q)
  int lm = lane & 15, kg = lane >> 4;
  int l3 = lane >> 3, l7 = lane & 7;
  int lm7 = lm & 7;

  int asbase = 496 - 16 * st;
  // staging sources (advance 64 shorts per chunk); both LDS layouts are
  // XOR-swizzled via pre-swizzled source (l7^l3), LDS dest stays linear.
  const short* bSrc = Hb + (size_t)(q0 + wid * 32 + l3) * S_LEN + ((l7 ^ l3) << 3);
  const short* aSrc = cp + ((size_t)(b * 8 + (l7 ^ l3)) * CPROWS + asbase + wid * 8 + l3) * 8;

  // A-frag offsets: data unit delta = dbase + 32*ks - 16*mf; read at swizzled
  // unit (d&~7)|((d&7)^((d>>3)&7)). Dedup: (ks1,mf2)=(ks0,mf0),(ks1,mf3)=(ks0,mf1).
  int dbase = 127 - 64 * wr - lm + 8 * kg;
  int aof[6];
  #pragma unroll
  for (int i = 0; i < 6; ++i) {
    int d = (i < 4) ? (dbase - 16 * i) : (dbase + 96 - 16 * i);  // i=4:+32, i=5:+16
    aof[i] = ((d & ~7) | ((d & 7) ^ ((d >> 3) & 7))) << 3;       // shorts
  }
  int bRow = (wc * 64 + lm) * 64;
  int bof[8];
  #pragma unroll
  for (int nf = 0; nf < 4; ++nf)
    #pragma unroll
    for (int ks = 0; ks < 2; ++ks)
      bof[nf * 2 + ks] = bRow + nf * 1024 + (((ks << 5) + (kg << 3)) ^ (lm7 << 3));

  f32x4 acc[4][4];
  #pragma unroll
  for (int i = 0; i < 4; ++i)
    #pragma unroll
    for (int jn = 0; jn < 4; ++jn)
      acc[i][jn] = (f32x4){0.0f, 0.0f, 0.0f, 0.0f};

  int nchunks = 2 * st + 2;

  auto STAGE = [&](int cc) {
    int slot = cc & 3;
    int coff = cc * 64;
    #pragma unroll
    for (int i = 0; i < 4; ++i)
      gload16(bSrc + (size_t)i * 8 * S_LEN + coff, &Bt[slot][(wid * 32 + i * 8) * 64]);
    gload16(aSrc + coff, &Aw[slot][(wid * 8) * 64]);
  };

  STAGE(0);
  STAGE(1);

  for (int c = 0; c < nchunks; ++c) {
    if (c + 2 < nchunks) {
      STAGE(c + 2);
      asm volatile("s_waitcnt vmcnt(10)\n\ts_barrier" ::: "memory");
    } else if (c + 1 < nchunks) {
      asm volatile("s_waitcnt vmcnt(5)\n\ts_barrier" ::: "memory");
    } else {
      asm volatile("s_waitcnt vmcnt(0)\n\ts_barrier" ::: "memory");
    }
    const short* AwB = &Aw[c & 3][0];
    const short* BtB = &Bt[c & 3][0];
    short8 A[6];
    #pragma unroll
    for (int i = 0; i < 6; ++i) A[i] = *(const short8*)(AwB + aof[i]);
    short8 Bf[8];
    #pragma unroll
    for (int i = 0; i < 8; ++i) Bf[i] = *(const short8*)(BtB + bof[i]);
    __builtin_amdgcn_s_setprio(1);
    #pragma unroll
    for (int nf = 0; nf < 4; ++nf) {
      acc[0][nf] = __builtin_amdgcn_mfma_f32_16x16x32_bf16(A[0], Bf[nf * 2], acc[0][nf], 0, 0, 0);
      acc[1][nf] = __builtin_amdgcn_mfma_f32_16x16x32_bf16(A[1], Bf[nf * 2], acc[1][nf], 0, 0, 0);
      acc[2][nf] = __builtin_amdgcn_mfma_f32_16x16x32_bf16(A[2], Bf[nf * 2], acc[2][nf], 0, 0, 0);
      acc[3][nf] = __builtin_amdgcn_mfma_f32_16x16x32_bf16(A[3], Bf[nf * 2], acc[3][nf], 0, 0, 0);
    }
    #pragma unroll
    for (int nf = 0; nf < 4; ++nf) {
      acc[0][nf] = __builtin_amdgcn_mfma_f32_16x16x32_bf16(A[4], Bf[nf * 2 + 1], acc[0][nf], 0, 0, 0);
      acc[1][nf] = __builtin_amdgcn_mfma_f32_16x16x32_bf16(A[5], Bf[nf * 2 + 1], acc[1][nf], 0, 0, 0);
      acc[2][nf] = __builtin_amdgcn_mfma_f32_16x16x32_bf16(A[0], Bf[nf * 2 + 1], acc[2][nf], 0, 0, 0);
      acc[3][nf] = __builtin_amdgcn_mfma_f32_16x16x32_bf16(A[1], Bf[nf * 2 + 1], acc[3][nf], 0, 0, 0);
    }
    __builtin_amdgcn_s_setprio(0);
  }

  // C/D layout: col = lane&15, row = (lane>>4)*4 + reg
  #pragma unroll
  for (int mf = 0; mf < 4; ++mf)
    #pragma unroll
    for (int nf = 0; nf < 4; ++nf)
      #pragma unroll
      for (int j = 0; j < 4; ++j) {
        int s = s0 + wr * 64 + mf * 16 + kg * 4 + j;
        int q = q0 + wc * 64 + nf * 16 + lm;
        mx[(size_t)(b * S_LEN + s) * KTOT + q] = f2bf(acc[mf][nf][j]);
      }
}

// K3: h = relu(mx @ W_h + b_h); h_n extra write for s==4095 rows.
__global__ __launch_bounds__(256) void k_gemm2(const short* __restrict__ mx,
                                               const short* __restrict__ wht,
                                               const float* __restrict__ bh,
                                               float* __restrict__ out) {
  int idx = blockIdx.x;       // 512 = 256 row-tiles * 2 n-tiles
  int nt = idx & 1;
  int rt = idx >> 1;
  int R0 = rt << 7;

  int tid = threadIdx.x;
  int l = tid & 63, wid = tid >> 6;
  int wr = wid >> 1, wc = wid & 1;
  int lm = l & 15, kg = l >> 4;

  const short* Abase = mx  + (size_t)(R0 + wr * 64 + lm) * KTOT + 8 * kg;
  const short* Bbase = wht + (size_t)(nt * 128 + wc * 64 + lm) * KTOT + 8 * kg;

  f32x4 acc[4][4];
  #pragma unroll
  for (int i = 0; i < 4; ++i)
    #pragma unroll
    for (int jn = 0; jn < 4; ++jn)
      acc[i][jn] = (f32x4){0.0f, 0.0f, 0.0f, 0.0f};

  short8 ac[4], bc[4];
  #pragma unroll
  for (int mf = 0; mf < 4; ++mf) ac[mf] = *(const short8*)(Abase + mf * 16 * KTOT);
  #pragma unroll
  for (int nf = 0; nf < 4; ++nf) bc[nf] = *(const short8*)(Bbase + nf * 16 * KTOT);

  for (int t = 0; ; ++t) {
    bool more = (t + 1 < 12);
    short8 an[4], bn[4];
    if (more) {
      const short* a2 = Abase + (t + 1) * 32;
      const short* b2 = Bbase + (t + 1) * 32;
      #pragma unroll
      for (int mf = 0; mf < 4; ++mf) an[mf] = *(const short8*)(a2 + mf * 16 * KTOT);
      #pragma unroll
      for (int nf = 0; nf < 4; ++nf) bn[nf] = *(const short8*)(b2 + nf * 16 * KTOT);
    }
    #pragma unroll
    for (int mf = 0; mf < 4; ++mf)
      #pragma unroll
      for (int nf = 0; nf < 4; ++nf)
        acc[mf][nf] = __builtin_amdgcn_mfma_f32_16x16x32_bf16(ac[mf], bc[nf], acc[mf][nf], 0, 0, 0);
    if (!more) break;
    #pragma unroll
    for (int mf = 0; mf < 4; ++mf) ac[mf] = an[mf];
    #pragma unroll
    for (int nf = 0; nf < 4; ++nf) bc[nf] = bn[nf];
  }

  #pragma unroll
  for (int mf = 0; mf < 4; ++mf)
    #pragma unroll
    for (int nf = 0; nf < 4; ++nf) {
      int n = nt * 128 + wc * 64 + nf * 16 + lm;
      float bias = bh[n];
      #pragma unroll
      for (int j = 0; j < 4; ++j) {
        int R = R0 + wr * 64 + mf * 16 + kg * 4 + j;
        float v = acc[mf][nf][j] + bias;
        v = v > 0.0f ? v : 0.0f;
        out[(size_t)R * 256 + n] = v;
        if ((R & (S_LEN - 1)) == (S_LEN - 1))
          out[HN_OFF + (R >> 12) * 256 + n] = v;
      }
    }
}

extern "C" void kernel_launch(void* const* d_in, const int* in_sizes, int n_in,
                              void* d_out, int out_size, void* d_ws, size_t ws_size,
                              hipStream_t stream) {
  const float* x  = (const float*)d_in[0];
  const float* Wu = (const float*)d_in[1];
  const float* bu = (const float*)d_in[2];
  const float* Wh = (const float*)d_in[3];
  const float* bh = (const float*)d_in[4];
  const float* H  = (const float*)d_in[5];
  float* out = (float*)d_out;

  char* ws = (char*)d_ws;
  short* cp  = (short*)(ws + 131072);              // 8*8*544*8*2 = 557056 B
  short* Hb  = (short*)(ws + 688128);              // 2097152 B
  short* wht = (short*)(ws + 2785280);             // 196608 B
  short* mx  = (short*)(ws + 2981888);             // 25165824 B

  k_u   <<<8264, 256, 0, stream>>>(x, Wu, bu, mx, cp);
  k_misc<<<4480, 256, 0, stream>>>(H, Wh, Hb, wht);
  k_conv<<<512,  256, 0, stream>>>(cp, Hb, mx);
  k_gemm2<<<512, 256, 0, stream>>>(mx, wht, bh, out);
}